// Round 10
// baseline (19768.935 us; speedup 1.0000x reference)
//
#include <hip/hip_runtime.h>
#include <math.h>

// Forbid fma contraction for every expression in this file (np-matching arithmetic).
#pragma clang fp contract(off)

#define NB 8
#define NP 8192
#define NS 2048
#define NK 32

// Decision-critical f32 ops as raw VALU instructions — cannot be contracted.
__device__ __forceinline__ float fsub(float a, float b) {
  float r; asm("v_sub_f32 %0, %1, %2" : "=v"(r) : "v"(a), "v"(b)); return r;
}
__device__ __forceinline__ float fmul(float a, float b) {
  float r; asm("v_mul_f32 %0, %1, %2" : "=v"(r) : "v"(a), "v"(b)); return r;
}
__device__ __forceinline__ float fadd(float a, float b) {
  float r; asm("v_add_f32 %0, %1, %2" : "=v"(r) : "v"(a), "v"(b)); return r;
}

// ---------------- FPS (PASSED in R9 — unchanged) ----------------
__global__ __launch_bounds__(256) void fps_kernel(const float* __restrict__ xyz,
                                                  float* __restrict__ new_xyz) {
  __shared__ float pdl[256];
  __shared__ int   pil[256];
  __shared__ float candx[256], candy[256], candz[256];
  __shared__ float wdv[4];
  __shared__ int   wiv[4];
  __shared__ float bcast[3];
  const int b = blockIdx.x;
  const int tid = threadIdx.x;
  const float* xb = xyz + (size_t)b * NP * 3;
  float px[32], py[32], pz[32], dist[32];
  for (int j = 0; j < 32; j++) {
    int p = j * 256 + tid;
    px[j] = xb[p * 3 + 0]; py[j] = xb[p * 3 + 1]; pz[j] = xb[p * 3 + 2];
    dist[j] = 1e10f;
  }
  float fx = xb[0], fy = xb[1], fz = xb[2];
  for (int t = 0; t < NS; t++) {
    if (tid == 0) {
      float* o = new_xyz + ((size_t)b * NS + t) * 3;
      o[0] = fx; o[1] = fy; o[2] = fz;
    }
    float lmax = -1.0f; int larg = 0; float lx = fx, ly = fy, lz = fz;
    for (int j = 0; j < 32; j++) {
      float dx = fsub(px[j], fx);
      float dy = fsub(py[j], fy);
      float dz = fsub(pz[j], fz);
      float d = fadd(fadd(fmul(dx, dx), fmul(dy, dy)), fmul(dz, dz));
      float nd = fminf(dist[j], d);
      dist[j] = nd;
      if (nd > lmax) { lmax = nd; larg = j * 256 + tid; lx = px[j]; ly = py[j]; lz = pz[j]; }
    }
    pdl[tid] = lmax; pil[tid] = larg;
    candx[tid] = lx; candy[tid] = ly; candz[tid] = lz;
    __syncthreads();
    if ((tid & 63) == 0) {
      float m = pdl[tid]; int mi = pil[tid];
      for (int i = 1; i < 64; i++) {
        float d = pdl[tid + i]; int ii = pil[tid + i];
        if (d > m || (d == m && ii < mi)) { m = d; mi = ii; }
      }
      wdv[tid >> 6] = m; wiv[tid >> 6] = mi;
    }
    __syncthreads();
    if (tid == 0) {
      float m = wdv[0]; int mi = wiv[0];
      for (int w = 1; w < 4; w++) {
        if (wdv[w] > m || (wdv[w] == m && wiv[w] < mi)) { m = wdv[w]; mi = wiv[w]; }
      }
      int owner = mi & 255;
      bcast[0] = candx[owner]; bcast[1] = candy[owner]; bcast[2] = candz[owner];
    }
    __syncthreads();
    fx = bcast[0]; fy = bcast[1]; fz = bcast[2];
    __syncthreads();
  }
}

// ---------------- Fused ball query + gather + MLP + maxpool ----------------
// Keys: Sc/Sn = mul/add sums of squares (separate-ufunc semantics, no contraction);
// inner = FMA chain (numpy's AVX2-era leftover scalar loop is gcc-contracted);
// d2 = (Sc+Sn) - 2*inner unfused; key = sqrt(max(d2,0)). Ties -> lowest index.
// MLP: un-folded, np op order: y = (fma-chain dot) + b; ((g*(y-m))*r)+bt, r=1/sqrt(v+eps).
__global__ __launch_bounds__(256) void ball_mlp_kernel(
    const float* __restrict__ xyz, const float* __restrict__ points,
    const float* __restrict__ new_xyz,
    const float* __restrict__ w0, const float* __restrict__ b0, const float* __restrict__ g0,
    const float* __restrict__ bt0, const float* __restrict__ m0, const float* __restrict__ v0,
    const float* __restrict__ w1, const float* __restrict__ b1, const float* __restrict__ g1,
    const float* __restrict__ bt1, const float* __restrict__ m1, const float* __restrict__ v1,
    const float* __restrict__ w2, const float* __restrict__ b2, const float* __restrict__ g2,
    const float* __restrict__ bt2, const float* __restrict__ m2, const float* __restrict__ v2,
    float* __restrict__ out_pts) {
  __shared__ __align__(16) float smem[16368];   // 65472 B
  // ---- phase A ----
  float* sd         = smem;                      // 8192 f32 keys
  int* hist         = (int*)(smem + 8192);       // 256
  int* cnts         = (int*)(smem + 8448);       // 2
  unsigned* sprefix = (unsigned*)(smem + 8450);
  int* sbelow       = (int*)(smem + 8451);
  int* snear_s      = (int*)(smem + 8452);
  int* selA         = (int*)(smem + 8456);       // 32
  int* tib          = (int*)(smem + 8488);       // 1024 tie indices
  int* qsel         = (int*)(smem + 16336);      // 32 (survives into phase B)
  // ---- phase B (smem[0..15903]) ----
  float* w0s  = smem;             // 64*9   raw
  float* w1s  = smem + 576;       // 64*65  raw (stride 65)
  float* w2s  = smem + 4736;      // 128*65 raw
  float* bnb  = smem + 13056;     // 256 bias
  float* bnm  = smem + 13312;     // 256 mean
  float* bng  = smem + 13568;     // 256 gamma
  float* bnr  = smem + 13824;     // 256 r = 1/sqrt(v+eps)
  float* bnbt = smem + 14080;     // 256 beta
  float* gin  = smem + 14336;     // 32*9
  float* x1   = smem + 14624;     // 8*64
  float* x2   = smem + 15136;     // 8*64
  float* pmax = smem + 15648;     // 256

  const int cs = blockIdx.x;
  const int b = cs >> 11;
  const int tid = threadIdx.x;
  const float* xb = xyz + (size_t)b * NP * 3;
  const float cx = new_xyz[cs * 3 + 0], cy = new_xyz[cs * 3 + 1], cz = new_xyz[cs * 3 + 2];
  const float Sc = fadd(fadd(fmul(cx, cx), fmul(cy, cy)), fmul(cz, cz));
  for (int p = tid; p < NP; p += 256) {
    float x = xb[p * 3 + 0], y = xb[p * 3 + 1], z = xb[p * 3 + 2];
    float Sn    = fadd(fadd(fmul(x, x), fmul(y, y)), fmul(z, z));
    float inner = fmaf(cz, z, fmaf(cy, y, fmul(cx, x)));   // contracted leftover loop
    float d2    = fsub(fadd(Sc, Sn), fmul(2.0f, inner));
    sd[p] = __fsqrt_rn(fmaxf(d2, 0.0f));
  }
  // 4-round radix select of the 32nd-smallest key
  unsigned prefix = 0; int below = 0;
  for (int round = 0; round < 4; round++) {
    const int shift = 24 - 8 * round;
    hist[tid] = 0;
    __syncthreads();
    for (int p = tid; p < NP; p += 256) {
      unsigned kb = __float_as_uint(sd[p]);
      if (round == 0 || (kb >> (shift + 8)) == (prefix >> (shift + 8)))
        atomicAdd(&hist[(kb >> shift) & 255], 1);
    }
    __syncthreads();
    if (tid == 0) {
      int cum = below; unsigned bsel = 255;
      for (int i = 0; i < 256; i++) {
        int h = hist[i];
        if (cum + h >= NK) { bsel = (unsigned)i; break; }
        cum += h;
      }
      *sprefix = prefix | (bsel << shift);
      *sbelow = cum;
    }
    __syncthreads();
    prefix = *sprefix; below = *sbelow;
  }
  const unsigned K32 = prefix;
  if (tid < 2) cnts[tid] = 0;
  __syncthreads();
  for (int p = tid; p < NP; p += 256) {
    unsigned kb = __float_as_uint(sd[p]);
    if (kb < K32) { int q = atomicAdd(&cnts[0], 1); if (q < NK) selA[q] = p; }
    else if (kb == K32) { int q = atomicAdd(&cnts[1], 1); if (q < 1024) tib[q] = p; }
  }
  __syncthreads();
  const int n1 = cnts[0] < NK ? cnts[0] : NK;
  int nt = cnts[1]; if (nt > 1024) nt = 1024;
  if (tid == 0) {
    int need = NK - n1;
    for (int a = 0; a < need; a++) {       // ties -> lowest indices (top_k stable)
      int bj = -1; int bidx = 0x7fffffff;
      for (int j = 0; j < nt; j++) {
        int p = tib[j];
        if (p >= 0 && p < bidx) { bidx = p; bj = j; }
      }
      if (bj >= 0) { selA[n1 + a] = bidx; tib[bj] = -1; }
      else selA[n1 + a] = selA[0];
    }
    float bk = 1e30f; int bp = 0x7fffffff;  // nearest = (min key, min idx)
    for (int j = 0; j < NK; j++) {
      int p = selA[j]; float kk = sd[p];
      if (kk < bk || (kk == bk && p < bp)) { bk = kk; bp = p; }
    }
    *snear_s = bp;
  }
  __syncthreads();
  if (tid < NK) {
    int p = selA[tid];
    qsel[tid] = (sd[p] > 0.25f) ? *snear_s : p;
  }
  __syncthreads();

  // ---- phase B: MLP (np op order, un-folded BN) ----
  {
    int o; const float *gp, *vp, *bp, *mp, *btp;
    if (tid < 64)       { o = tid;       gp = g0; vp = v0; bp = b0; mp = m0; btp = bt0; }
    else if (tid < 128) { o = tid - 64;  gp = g1; vp = v1; bp = b1; mp = m1; btp = bt1; }
    else                { o = tid - 128; gp = g2; vp = v2; bp = b2; mp = m2; btp = bt2; }
    bnb[tid]  = bp[o];
    bnm[tid]  = mp[o];
    bng[tid]  = gp[o];
    bnbt[tid] = btp[o];
    bnr[tid]  = 1.0f / __fsqrt_rn(fadd(vp[o], 1e-5f));   // np: 1/sqrt(v+eps), f32 RN
  }
  for (int p = tid; p < 576; p += 256)  { w0s[p] = w0[p]; }
  for (int p = tid; p < 4096; p += 256) { int o = p >> 6, c = p & 63; w1s[o * 65 + c] = w1[p]; }
  for (int p = tid; p < 8192; p += 256) { int o = p >> 6, c = p & 63; w2s[o * 65 + c] = w2[p]; }
  for (int e = tid; e < 288; e += 256) {
    int k = e / 9, c = e % 9;
    int p = qsel[k];
    float v;
    if (c < 3) {
      float cc = (c == 0) ? cx : (c == 1 ? cy : cz);
      v = fsub(xyz[((size_t)b * NP + p) * 3 + c], cc);
    } else {
      v = points[((size_t)b * NP + p) * 6 + (c - 3)];
    }
    gin[k * 9 + c] = v;
  }
  __syncthreads();
  float lm = -1e30f;
  for (int h = 0; h < 4; h++) {           // 8 k's per tile
    { // L1: 8k x 64o
      int o = tid & 63, k0 = (tid >> 6) * 2;
      for (int j = 0; j < 2; j++) {
        int k = k0 + j, kg = h * 8 + k;
        float acc = 0.f;
        for (int c = 0; c < 9; c++) acc = fmaf(w0s[o * 9 + c], gin[kg * 9 + c], acc);
        float y = fadd(acc, bnb[o]);
        y = fadd(fmul(fmul(bng[o], fsub(y, bnm[o])), bnr[o]), bnbt[o]);
        x1[k * 64 + o] = fmaxf(y, 0.f);
      }
    }
    __syncthreads();
    { // L2: 64 -> 64
      int o = tid & 63, k0 = (tid >> 6) * 2;
      for (int j = 0; j < 2; j++) {
        int k = k0 + j;
        float acc = 0.f;
        for (int c = 0; c < 64; c++) acc = fmaf(w1s[o * 65 + c], x1[k * 64 + c], acc);
        float y = fadd(acc, bnb[64 + o]);
        y = fadd(fmul(fmul(bng[64 + o], fsub(y, bnm[64 + o])), bnr[64 + o]), bnbt[64 + o]);
        x2[k * 64 + o] = fmaxf(y, 0.f);
      }
    }
    __syncthreads();
    { // L3: 64 -> 128 + running max over k
      int ch = tid & 127, k0 = (tid >> 7) * 4;
      for (int j = 0; j < 4; j++) {
        int k = k0 + j;
        float acc = 0.f;
        for (int c = 0; c < 64; c++) acc = fmaf(w2s[ch * 65 + c], x2[k * 64 + c], acc);
        float y = fadd(acc, bnb[128 + ch]);
        y = fadd(fmul(fmul(bng[128 + ch], fsub(y, bnm[128 + ch])), bnr[128 + ch]), bnbt[128 + ch]);
        lm = fmaxf(lm, fmaxf(y, 0.f));
      }
    }
    __syncthreads();
  }
  pmax[tid] = lm;
  __syncthreads();
  if (tid < 128) {
    out_pts[(size_t)cs * 128 + tid] = fmaxf(pmax[tid], pmax[128 + tid]);
  }
}

extern "C" void kernel_launch(void* const* d_in, const int* in_sizes, int n_in,
                              void* d_out, int out_size, void* d_ws, size_t ws_size,
                              hipStream_t stream) {
  (void)in_sizes; (void)n_in; (void)out_size; (void)d_ws; (void)ws_size;
  const float* xyz    = (const float*)d_in[0];
  const float* points = (const float*)d_in[1];
  const float* w0 = (const float*)d_in[2];
  const float* b0 = (const float*)d_in[3];
  const float* g0 = (const float*)d_in[4];
  const float* bt0 = (const float*)d_in[5];
  const float* m0 = (const float*)d_in[6];
  const float* v0 = (const float*)d_in[7];
  const float* w1 = (const float*)d_in[8];
  const float* b1 = (const float*)d_in[9];
  const float* g1 = (const float*)d_in[10];
  const float* bt1 = (const float*)d_in[11];
  const float* m1 = (const float*)d_in[12];
  const float* v1 = (const float*)d_in[13];
  const float* w2 = (const float*)d_in[14];
  const float* b2 = (const float*)d_in[15];
  const float* g2 = (const float*)d_in[16];
  const float* bt2 = (const float*)d_in[17];
  const float* m2 = (const float*)d_in[18];
  const float* v2 = (const float*)d_in[19];

  float* new_xyz = (float*)d_out;                         // 8*2048*3 f32
  float* out_pts = (float*)d_out + (size_t)NB * NS * 3;   // 8*2048*128 f32

  fps_kernel<<<NB, 256, 0, stream>>>(xyz, new_xyz);
  ball_mlp_kernel<<<NB * NS, 256, 0, stream>>>(xyz, points, new_xyz,
                                               w0, b0, g0, bt0, m0, v0,
                                               w1, b1, g1, bt1, m1, v1,
                                               w2, b2, g2, bt2, m2, v2,
                                               out_pts);
}

// Round 11
// 5238.523 us; speedup vs baseline: 3.7738x; 3.7738x over previous
//
#include <hip/hip_runtime.h>
#include <math.h>

// Forbid fma contraction for every expression in this file (np-matching arithmetic).
#pragma clang fp contract(off)

#define NB 8
#define NP 8192
#define NS 2048
#define NK 32

// Decision-critical f32 ops as raw VALU instructions — cannot be contracted.
__device__ __forceinline__ float fsub(float a, float b) {
  float r; asm("v_sub_f32 %0, %1, %2" : "=v"(r) : "v"(a), "v"(b)); return r;
}
__device__ __forceinline__ float fmul(float a, float b) {
  float r; asm("v_mul_f32 %0, %1, %2" : "=v"(r) : "v"(a), "v"(b)); return r;
}
__device__ __forceinline__ float fadd(float a, float b) {
  float r; asm("v_add_f32 %0, %1, %2" : "=v"(r) : "v"(a), "v"(b)); return r;
}

// ---------------- FPS: 512 threads x 16 pts (64 VGPRs of data -> no spill) ----------------
// Same exact unfused math as the R10 passing kernel. Reduction: pack (key<<32 | ~idx)
// into u64; unsigned max == (max key, then lowest index) == np.argmax first-occurrence.
// 6 shuffle steps in-register + one 8-entry LDS stage; 2 barriers/iter (was 4).
__global__ __launch_bounds__(512, 1) void fps_kernel(const float* __restrict__ xyz,
                                                     float* __restrict__ new_xyz) {
  __shared__ float candx[512], candy[512], candz[512];
  __shared__ unsigned long long wbest[8];
  __shared__ float bcast[3];
  const int b = blockIdx.x;
  const int tid = threadIdx.x;
  const int lane = tid & 63, wv = tid >> 6;
  const float* xb = xyz + (size_t)b * NP * 3;
  float px[16], py[16], pz[16], dist[16];
#pragma unroll
  for (int j = 0; j < 16; j++) {
    int p = j * 512 + tid;
    px[j] = xb[p * 3 + 0]; py[j] = xb[p * 3 + 1]; pz[j] = xb[p * 3 + 2];
    dist[j] = 1e10f;
  }
  float fx = xb[0], fy = xb[1], fz = xb[2];   // farthest = index 0 at t=0
  for (int t = 0; t < NS; t++) {
    if (tid == 0) {
      float* o = new_xyz + ((size_t)b * NS + t) * 3;
      o[0] = fx; o[1] = fy; o[2] = fz;
    }
    float lmax = -1.0f; int larg = 0; float lx = fx, ly = fy, lz = fz;
#pragma unroll
    for (int j = 0; j < 16; j++) {
      float dx = fsub(px[j], fx);
      float dy = fsub(py[j], fy);
      float dz = fsub(pz[j], fz);
      float d = fadd(fadd(fmul(dx, dx), fmul(dy, dy)), fmul(dz, dz));
      float nd = fminf(dist[j], d);
      dist[j] = nd;
      // ascending j => ascending global idx for this thread: strict '>' keeps lowest idx
      if (nd > lmax) { lmax = nd; larg = j * 512 + tid; lx = px[j]; ly = py[j]; lz = pz[j]; }
    }
    candx[tid] = lx; candy[tid] = ly; candz[tid] = lz;
    // dist >= 0 => key bits unsigned-monotone; ~idx makes u64-max pick lowest idx on ties
    unsigned long long m = ((unsigned long long)__float_as_uint(lmax) << 32)
                         | (unsigned long long)(unsigned)(~(unsigned)larg);
#pragma unroll
    for (int off = 32; off > 0; off >>= 1) {
      unsigned long long o2 = __shfl_down(m, off);
      if (o2 > m) m = o2;
    }
    if (lane == 0) wbest[wv] = m;
    __syncthreads();
    if (tid == 0) {
      unsigned long long mm = wbest[0];
#pragma unroll
      for (int w = 1; w < 8; w++) if (wbest[w] > mm) mm = wbest[w];
      unsigned widx = ~(unsigned)(mm & 0xFFFFFFFFull);
      int owner = (int)(widx & 511u);        // idx = j*512 + tid
      bcast[0] = candx[owner]; bcast[1] = candy[owner]; bcast[2] = candz[owner];
    }
    __syncthreads();
    fx = bcast[0]; fy = bcast[1]; fz = bcast[2];
    // no 3rd barrier needed: next-iter candx writes happen after this read point on
    // every thread, and tid0's candx reads completed before the barrier above.
  }
}

// ---------------- Fused ball query + gather + MLP + maxpool ----------------
// Phase A numerics IDENTICAL to the R10 passing kernel. Phase B: same fmaf chain
// order, but weights at stride 68 (16B-aligned) -> ds_read_b128 for w and x tiles.
__global__ __launch_bounds__(256) void ball_mlp_kernel(
    const float* __restrict__ xyz, const float* __restrict__ points,
    const float* __restrict__ new_xyz,
    const float* __restrict__ w0, const float* __restrict__ b0, const float* __restrict__ g0,
    const float* __restrict__ bt0, const float* __restrict__ m0, const float* __restrict__ v0,
    const float* __restrict__ w1, const float* __restrict__ b1, const float* __restrict__ g1,
    const float* __restrict__ bt1, const float* __restrict__ m1, const float* __restrict__ v1,
    const float* __restrict__ w2, const float* __restrict__ b2, const float* __restrict__ g2,
    const float* __restrict__ bt2, const float* __restrict__ m2, const float* __restrict__ v2,
    float* __restrict__ out_pts) {
  __shared__ __align__(16) float smem[16256];   // 65024 B < 64 KiB
  // ---- phase A ----
  float* sd         = smem;                      // 8192 f32 keys
  int* hist         = (int*)(smem + 8192);       // 256
  int* cnts         = (int*)(smem + 8448);       // 2
  unsigned* sprefix = (unsigned*)(smem + 8450);
  int* sbelow       = (int*)(smem + 8451);
  int* snear_s      = (int*)(smem + 8452);
  int* selA         = (int*)(smem + 8456);       // 32
  int* tib          = (int*)(smem + 8488);       // 1024 tie indices
  int* qsel         = (int*)(smem + 16224);      // 32 (survives into phase B)
  // ---- phase B ----
  float* w0s  = smem;             // 64*9
  float* w1s  = smem + 576;       // 64*68  (stride 68: 16B-aligned, 17-odd banks)
  float* w2s  = smem + 4928;      // 128*68
  float* bnb  = smem + 13632;     // 256
  float* bnm  = smem + 13888;     // 256
  float* bng  = smem + 14144;     // 256
  float* bnr  = smem + 14400;     // 256
  float* bnbt = smem + 14656;     // 256
  float* gin  = smem + 14912;     // 32*9
  float* x1   = smem + 15200;     // 8*64
  float* x2   = smem + 15712;     // 8*64
  float* pmax = smem + 15200;     // 256, overlays x1 (dead by the time pmax is written)

  const int cs = blockIdx.x;
  const int b = cs >> 11;
  const int tid = threadIdx.x;
  const float* xb = xyz + (size_t)b * NP * 3;
  const float cx = new_xyz[cs * 3 + 0], cy = new_xyz[cs * 3 + 1], cz = new_xyz[cs * 3 + 2];
  const float Sc = fadd(fadd(fmul(cx, cx), fmul(cy, cy)), fmul(cz, cz));
  for (int p = tid; p < NP; p += 256) {
    float x = xb[p * 3 + 0], y = xb[p * 3 + 1], z = xb[p * 3 + 2];
    float Sn    = fadd(fadd(fmul(x, x), fmul(y, y)), fmul(z, z));
    float inner = fmaf(cz, z, fmaf(cy, y, fmul(cx, x)));
    float d2    = fsub(fadd(Sc, Sn), fmul(2.0f, inner));
    sd[p] = __fsqrt_rn(fmaxf(d2, 0.0f));
  }
  // 4-round radix select of the 32nd-smallest key
  unsigned prefix = 0; int below = 0;
  for (int round = 0; round < 4; round++) {
    const int shift = 24 - 8 * round;
    hist[tid] = 0;
    __syncthreads();
    for (int p = tid; p < NP; p += 256) {
      unsigned kb = __float_as_uint(sd[p]);
      if (round == 0 || (kb >> (shift + 8)) == (prefix >> (shift + 8)))
        atomicAdd(&hist[(kb >> shift) & 255], 1);
    }
    __syncthreads();
    if (tid == 0) {
      int cum = below; unsigned bsel = 255;
      for (int i = 0; i < 256; i++) {
        int h = hist[i];
        if (cum + h >= NK) { bsel = (unsigned)i; break; }
        cum += h;
      }
      *sprefix = prefix | (bsel << shift);
      *sbelow = cum;
    }
    __syncthreads();
    prefix = *sprefix; below = *sbelow;
  }
  const unsigned K32 = prefix;
  if (tid < 2) cnts[tid] = 0;
  __syncthreads();
  for (int p = tid; p < NP; p += 256) {
    unsigned kb = __float_as_uint(sd[p]);
    if (kb < K32) { int q = atomicAdd(&cnts[0], 1); if (q < NK) selA[q] = p; }
    else if (kb == K32) { int q = atomicAdd(&cnts[1], 1); if (q < 1024) tib[q] = p; }
  }
  __syncthreads();
  const int n1 = cnts[0] < NK ? cnts[0] : NK;
  int nt = cnts[1]; if (nt > 1024) nt = 1024;
  if (tid == 0) {
    int need = NK - n1;
    for (int a = 0; a < need; a++) {       // ties -> lowest indices (top_k stable)
      int bj = -1; int bidx = 0x7fffffff;
      for (int j = 0; j < nt; j++) {
        int p = tib[j];
        if (p >= 0 && p < bidx) { bidx = p; bj = j; }
      }
      if (bj >= 0) { selA[n1 + a] = bidx; tib[bj] = -1; }
      else selA[n1 + a] = selA[0];
    }
    float bk = 1e30f; int bp = 0x7fffffff;  // nearest = (min key, min idx)
    for (int j = 0; j < NK; j++) {
      int p = selA[j]; float kk = sd[p];
      if (kk < bk || (kk == bk && p < bp)) { bk = kk; bp = p; }
    }
    *snear_s = bp;
  }
  __syncthreads();
  if (tid < NK) {
    int p = selA[tid];
    qsel[tid] = (sd[p] > 0.25f) ? *snear_s : p;
  }
  __syncthreads();

  // ---- phase B: MLP (np op order, un-folded BN; identical arithmetic to R10) ----
  {
    int o; const float *gp, *vp, *bp, *mp, *btp;
    if (tid < 64)       { o = tid;       gp = g0; vp = v0; bp = b0; mp = m0; btp = bt0; }
    else if (tid < 128) { o = tid - 64;  gp = g1; vp = v1; bp = b1; mp = m1; btp = bt1; }
    else                { o = tid - 128; gp = g2; vp = v2; bp = b2; mp = m2; btp = bt2; }
    bnb[tid]  = bp[o];
    bnm[tid]  = mp[o];
    bng[tid]  = gp[o];
    bnbt[tid] = btp[o];
    bnr[tid]  = 1.0f / __fsqrt_rn(fadd(vp[o], 1e-5f));
  }
  for (int p = tid; p < 576; p += 256)  { w0s[p] = w0[p]; }
  for (int p = tid; p < 4096; p += 256) { int o = p >> 6, c = p & 63; w1s[o * 68 + c] = w1[p]; }
  for (int p = tid; p < 8192; p += 256) { int o = p >> 6, c = p & 63; w2s[o * 68 + c] = w2[p]; }
  for (int e = tid; e < 288; e += 256) {
    int k = e / 9, c = e % 9;
    int p = qsel[k];
    float v;
    if (c < 3) {
      float cc = (c == 0) ? cx : (c == 1 ? cy : cz);
      v = fsub(xyz[((size_t)b * NP + p) * 3 + c], cc);
    } else {
      v = points[((size_t)b * NP + p) * 6 + (c - 3)];
    }
    gin[k * 9 + c] = v;
  }
  __syncthreads();
  float lm = -1e30f;
  for (int h = 0; h < 4; h++) {           // 8 k's per tile
    { // L1: 8k x 64o
      int o = tid & 63, k0 = (tid >> 6) * 2;
      for (int j = 0; j < 2; j++) {
        int k = k0 + j, kg = h * 8 + k;
        float acc = 0.f;
        for (int c = 0; c < 9; c++) acc = fmaf(w0s[o * 9 + c], gin[kg * 9 + c], acc);
        float y = fadd(acc, bnb[o]);
        y = fadd(fmul(fmul(bng[o], fsub(y, bnm[o])), bnr[o]), bnbt[o]);
        x1[k * 64 + o] = fmaxf(y, 0.f);
      }
    }
    __syncthreads();
    { // L2: 64 -> 64 (b128 LDS loads, chain order preserved: c ascending)
      int o = tid & 63, k0 = (tid >> 6) * 2;
      for (int j = 0; j < 2; j++) {
        int k = k0 + j;
        float acc = 0.f;
        for (int c4 = 0; c4 < 16; c4++) {
          const float4 wv4 = *(const float4*)&w1s[o * 68 + 4 * c4];
          const float4 xv  = *(const float4*)&x1[k * 64 + 4 * c4];
          acc = fmaf(wv4.x, xv.x, acc);
          acc = fmaf(wv4.y, xv.y, acc);
          acc = fmaf(wv4.z, xv.z, acc);
          acc = fmaf(wv4.w, xv.w, acc);
        }
        float y = fadd(acc, bnb[64 + o]);
        y = fadd(fmul(fmul(bng[64 + o], fsub(y, bnm[64 + o])), bnr[64 + o]), bnbt[64 + o]);
        x2[k * 64 + o] = fmaxf(y, 0.f);
      }
    }
    __syncthreads();
    { // L3: 64 -> 128 + running max over k (b128 LDS loads)
      int ch = tid & 127, k0 = (tid >> 7) * 4;
      for (int j = 0; j < 4; j++) {
        int k = k0 + j;
        float acc = 0.f;
        for (int c4 = 0; c4 < 16; c4++) {
          const float4 wv4 = *(const float4*)&w2s[ch * 68 + 4 * c4];
          const float4 xv  = *(const float4*)&x2[k * 64 + 4 * c4];
          acc = fmaf(wv4.x, xv.x, acc);
          acc = fmaf(wv4.y, xv.y, acc);
          acc = fmaf(wv4.z, xv.z, acc);
          acc = fmaf(wv4.w, xv.w, acc);
        }
        float y = fadd(acc, bnb[128 + ch]);
        y = fadd(fmul(fmul(bng[128 + ch], fsub(y, bnm[128 + ch])), bnr[128 + ch]), bnbt[128 + ch]);
        lm = fmaxf(lm, fmaxf(y, 0.f));
      }
    }
    __syncthreads();
  }
  pmax[tid] = lm;                 // overlays x1 (x1 dead after final L2->L3 consumed)
  __syncthreads();
  if (tid < 128) {
    out_pts[(size_t)cs * 128 + tid] = fmaxf(pmax[tid], pmax[128 + tid]);
  }
}

extern "C" void kernel_launch(void* const* d_in, const int* in_sizes, int n_in,
                              void* d_out, int out_size, void* d_ws, size_t ws_size,
                              hipStream_t stream) {
  (void)in_sizes; (void)n_in; (void)out_size; (void)d_ws; (void)ws_size;
  const float* xyz    = (const float*)d_in[0];
  const float* points = (const float*)d_in[1];
  const float* w0 = (const float*)d_in[2];
  const float* b0 = (const float*)d_in[3];
  const float* g0 = (const float*)d_in[4];
  const float* bt0 = (const float*)d_in[5];
  const float* m0 = (const float*)d_in[6];
  const float* v0 = (const float*)d_in[7];
  const float* w1 = (const float*)d_in[8];
  const float* b1 = (const float*)d_in[9];
  const float* g1 = (const float*)d_in[10];
  const float* bt1 = (const float*)d_in[11];
  const float* m1 = (const float*)d_in[12];
  const float* v1 = (const float*)d_in[13];
  const float* w2 = (const float*)d_in[14];
  const float* b2 = (const float*)d_in[15];
  const float* g2 = (const float*)d_in[16];
  const float* bt2 = (const float*)d_in[17];
  const float* m2 = (const float*)d_in[18];
  const float* v2 = (const float*)d_in[19];

  float* new_xyz = (float*)d_out;                         // 8*2048*3 f32
  float* out_pts = (float*)d_out + (size_t)NB * NS * 3;   // 8*2048*128 f32

  fps_kernel<<<NB, 512, 0, stream>>>(xyz, new_xyz);
  ball_mlp_kernel<<<NB * NS, 256, 0, stream>>>(xyz, points, new_xyz,
                                               w0, b0, g0, bt0, m0, v0,
                                               w1, b1, g1, bt1, m1, v1,
                                               w2, b2, g2, bt2, m2, v2,
                                               out_pts);
}